// Round 1
// baseline (849.221 us; speedup 1.0000x reference)
//
#include <hip/hip_runtime.h>

#define N_NODES 100000
#define NEDGE   1600000
#define NHID    128
#define NCLASS  40

using bf16x8 = __attribute__((ext_vector_type(8))) short;
using f32x4  = __attribute__((ext_vector_type(4))) float;

__device__ __forceinline__ float bf2f(unsigned short s) {
    unsigned u = ((unsigned)s) << 16; float f; __builtin_memcpy(&f, &u, 4); return f;
}
__device__ __forceinline__ unsigned short f2bf(float f) {
    unsigned u; __builtin_memcpy(&u, &f, 4);
    u = u + 0x7fffu + ((u >> 16) & 1u);          // RNE
    return (unsigned short)(u >> 16);
}

// ---------------- CSR build ----------------
__global__ void k_zero(int* __restrict__ p, int n) {
    int i = blockIdx.x * 256 + threadIdx.x;
    if (i < n) p[i] = 0;
}

__global__ void k_count(const int* __restrict__ ei, int* __restrict__ cnt) {
    int e = blockIdx.x * 256 + threadIdx.x;
    if (e < NEDGE) atomicAdd(&cnt[ei[NEDGE + e]], 1);   // dst row of edge_index
}

// block scans 1024 elements (256 thr x 4)
__global__ void k_scan1(const int* __restrict__ cnt, int* __restrict__ rp, int* __restrict__ bsum) {
    __shared__ int sh[256];
    int t = threadIdx.x, base = blockIdx.x * 1024;
    int v[4]; int s = 0;
    for (int k = 0; k < 4; ++k) { int i = base + t * 4 + k; v[k] = (i < N_NODES) ? cnt[i] : 0; s += v[k]; }
    sh[t] = s; __syncthreads();
    for (int off = 1; off < 256; off <<= 1) {
        int x = (t >= off) ? sh[t - off] : 0;
        __syncthreads();
        sh[t] += x;
        __syncthreads();
    }
    int excl = sh[t] - s;
    for (int k = 0; k < 4; ++k) { int i = base + t * 4 + k; if (i < N_NODES) rp[i] = excl; excl += v[k]; }
    if (t == 255) bsum[blockIdx.x] = sh[255];
}

__global__ void k_scan2(int* __restrict__ bsum, int nb) {
    __shared__ int sh[256];
    int t = threadIdx.x;
    int v = (t < nb) ? bsum[t] : 0;
    sh[t] = v; __syncthreads();
    for (int off = 1; off < 256; off <<= 1) {
        int x = (t >= off) ? sh[t - off] : 0;
        __syncthreads();
        sh[t] += x;
        __syncthreads();
    }
    if (t < nb) bsum[t] = sh[t] - v;   // exclusive block offsets
}

__global__ void k_scan3(int* __restrict__ rp, const int* __restrict__ bsum) {
    int base = blockIdx.x * 1024;
    int off = bsum[blockIdx.x];
    for (int k = 0; k < 4; ++k) {
        int i = base + threadIdx.x * 4 + k;
        if (i < N_NODES) rp[i] += off;
    }
    if (blockIdx.x == 0 && threadIdx.x == 0) rp[N_NODES] = NEDGE;
}

__global__ void k_fill(const int* __restrict__ ei, const int* __restrict__ rp,
                       int* __restrict__ cur, int* __restrict__ colv) {
    int e = blockIdx.x * 256 + threadIdx.x;
    if (e < NEDGE) {
        int d = ei[NEDGE + e];
        int p = atomicAdd(&cur[d], 1);
        colv[rp[d] + p] = ei[e];
    }
}

// ---------------- weight prep: transpose + cvt to bf16, wt[o][k] = w[k][o] ----------------
__global__ void k_wprep(const float* __restrict__ w, unsigned short* __restrict__ wt,
                        int K, int O, int Opad) {
    int idx = blockIdx.x * 256 + threadIdx.x;
    if (idx >= K * Opad) return;
    int o = idx / K, k = idx - o * K;
    float v = (o < O) ? w[k * O + o] : 0.f;
    wt[idx] = f2bf(v);
}

// ---------------- aggregation: t[i] = F[i] + sum_{j in N(i)} F[j], bf16 out ----------------
template <int F32>
__global__ void k_agg(const void* __restrict__ feat, unsigned short* __restrict__ tout,
                      const int* __restrict__ rp, const int* __restrict__ colv) {
    int node = blockIdx.x * 4 + (threadIdx.x >> 6);
    if (node >= N_NODES) return;
    int lane = threadIdx.x & 63;          // lane covers dims 2*lane, 2*lane+1
    float a0, a1;
    if (F32) {
        float2 v = *((const float2*)feat + (size_t)node * 64 + lane);
        a0 = v.x; a1 = v.y;
    } else {
        unsigned u = *((const unsigned*)feat + (size_t)node * 64 + lane);
        a0 = bf2f((unsigned short)u); a1 = bf2f((unsigned short)(u >> 16));
    }
    int e0 = rp[node], e1 = rp[node + 1];
    for (int e = e0; e < e1; ++e) {
        int j = colv[e];
        if (F32) {
            float2 v = *((const float2*)feat + (size_t)j * 64 + lane);
            a0 += v.x; a1 += v.y;
        } else {
            unsigned u = *((const unsigned*)feat + (size_t)j * 64 + lane);
            a0 += bf2f((unsigned short)u); a1 += bf2f((unsigned short)(u >> 16));
        }
    }
    unsigned o = (unsigned)f2bf(a0) | ((unsigned)f2bf(a1) << 16);
    *((unsigned*)tout + (size_t)node * 64 + lane) = o;
}

// ---------------- fused GIN MLP: h = relu(relu(t@w1+b1)@w2+b2), 64-node tile ----------------
__global__ __launch_bounds__(256) void k_mlp(
    const unsigned short* __restrict__ tin,
    const unsigned short* __restrict__ w1t, const float* __restrict__ b1,
    const unsigned short* __restrict__ w2t, const float* __restrict__ b2,
    unsigned short* __restrict__ hout) {
    __shared__ __align__(16) char tlds[64 * 256];
    __shared__ __align__(16) char hlds[64 * 256];
    const int tid = threadIdx.x, lane = tid & 63, w = tid >> 6;
    const int l15 = lane & 15, lg = lane >> 4;
    const int nbase = blockIdx.x * 64;

    // stage t tile (swizzled)
    for (int i = 0; i < 4; ++i) {
        int idx = i * 256 + tid, r = idx >> 4, c8 = idx & 15;
        int4 val{0, 0, 0, 0};
        int node = nbase + r;
        if (node < N_NODES) val = *(const int4*)(tin + (size_t)node * 128 + c8 * 8);
        *(int4*)(tlds + r * 256 + ((c8 * 16) ^ ((r & 7) << 4))) = val;
    }

    // preload B1 fragments + bias (wave w owns out cols [32w, 32w+32))
    bf16x8 B1[2][4]; float bias1[2]; int cols[2];
    for (int ot = 0; ot < 2; ++ot) {
        int c = (w * 2 + ot) * 16 + l15;
        cols[ot] = c; bias1[ot] = b1[c];
        for (int ks = 0; ks < 4; ++ks)
            B1[ot][ks] = *(const bf16x8*)(w1t + (size_t)c * 128 + ks * 32 + lg * 8);
    }
    __syncthreads();

    // GEMM1 -> relu -> hlds
    for (int m = 0; m < 4; ++m) {
        bf16x8 A[4];
        for (int ks = 0; ks < 4; ++ks) {
            int row = m * 16 + l15;
            A[ks] = *(const bf16x8*)(tlds + row * 256 + ((ks * 64 + lg * 16) ^ ((row & 7) << 4)));
        }
        for (int ot = 0; ot < 2; ++ot) {
            f32x4 acc = {0.f, 0.f, 0.f, 0.f};
            for (int ks = 0; ks < 4; ++ks)
                acc = __builtin_amdgcn_mfma_f32_16x16x32_bf16(A[ks], B1[ot][ks], acc, 0, 0, 0);
            int c2 = cols[ot] * 2;
            for (int r = 0; r < 4; ++r) {
                int row = m * 16 + lg * 4 + r;
                float v = acc[r] + bias1[ot]; v = v > 0.f ? v : 0.f;
                *(unsigned short*)(hlds + row * 256 + (c2 ^ ((row & 7) << 4))) = f2bf(v);
            }
        }
    }

    // preload B2
    bf16x8 B2[2][4]; float bias2[2];
    for (int ot = 0; ot < 2; ++ot) {
        int c = cols[ot];
        bias2[ot] = b2[c];
        for (int ks = 0; ks < 4; ++ks)
            B2[ot][ks] = *(const bf16x8*)(w2t + (size_t)c * 128 + ks * 32 + lg * 8);
    }
    __syncthreads();

    // GEMM2 -> relu -> global
    for (int m = 0; m < 4; ++m) {
        bf16x8 A[4];
        for (int ks = 0; ks < 4; ++ks) {
            int row = m * 16 + l15;
            A[ks] = *(const bf16x8*)(hlds + row * 256 + ((ks * 64 + lg * 16) ^ ((row & 7) << 4)));
        }
        for (int ot = 0; ot < 2; ++ot) {
            f32x4 acc = {0.f, 0.f, 0.f, 0.f};
            for (int ks = 0; ks < 4; ++ks)
                acc = __builtin_amdgcn_mfma_f32_16x16x32_bf16(A[ks], B2[ot][ks], acc, 0, 0, 0);
            for (int r = 0; r < 4; ++r) {
                int node = nbase + m * 16 + lg * 4 + r;
                if (node < N_NODES) {
                    float v = acc[r] + bias2[ot]; v = v > 0.f ? v : 0.f;
                    hout[(size_t)node * 128 + cols[ot]] = f2bf(v);
                }
            }
        }
    }
}

// ---------------- fused head: relu(concat@lin1+b) @ lin2 + b -> log_softmax ----------------
__global__ __launch_bounds__(256) void k_final(
    const unsigned short* __restrict__ h1, const unsigned short* __restrict__ h2,
    const unsigned short* __restrict__ h3,
    const unsigned short* __restrict__ l1t, const float* __restrict__ l1b,
    const unsigned short* __restrict__ l2t, const float* __restrict__ l2b,
    float* __restrict__ out) {
    __shared__ __align__(16) char lds[64 * 768];   // 48KB: A-tile then hidden
    const int tid = threadIdx.x, lane = tid & 63, w = tid >> 6;
    const int l15 = lane & 15, lg = lane >> 4;
    const int nbase = blockIdx.x * 64;

    // stage concat(h1,h2,h3) tile, swizzled
    for (int i = 0; i < 12; ++i) {
        int idx = i * 256 + tid;
        int r = idx / 48, c8 = idx - r * 48;
        int part = c8 >> 4, cc = c8 & 15;
        const unsigned short* hp = part == 0 ? h1 : (part == 1 ? h2 : h3);
        int4 val{0, 0, 0, 0};
        int node = nbase + r;
        if (node < N_NODES) val = *(const int4*)(hp + (size_t)node * 128 + cc * 8);
        *(int4*)(lds + r * 768 + ((c8 * 16) ^ ((r & 7) << 4))) = val;
    }
    __syncthreads();

    // lin1: wave w owns out cols [96w, 96w+96)
    f32x4 acc[4][6];
    for (int m = 0; m < 4; ++m)
        for (int ot = 0; ot < 6; ++ot) acc[m][ot] = {0.f, 0.f, 0.f, 0.f};
    for (int ks = 0; ks < 12; ++ks) {
        bf16x8 A[4];
        for (int m = 0; m < 4; ++m) {
            int row = m * 16 + l15;
            A[m] = *(const bf16x8*)(lds + row * 768 + ((ks * 64 + lg * 16) ^ ((row & 7) << 4)));
        }
        for (int ot = 0; ot < 6; ++ot) {
            int c = (w * 6 + ot) * 16 + l15;
            bf16x8 B = *(const bf16x8*)(l1t + (size_t)c * 384 + ks * 32 + lg * 8);
            for (int m = 0; m < 4; ++m)
                acc[m][ot] = __builtin_amdgcn_mfma_f32_16x16x32_bf16(A[m], B, acc[m][ot], 0, 0, 0);
        }
    }
    __syncthreads();   // everyone done reading A-tile

    // relu + write hidden (bf16) into same LDS
    for (int ot = 0; ot < 6; ++ot) {
        int c = (w * 6 + ot) * 16 + l15;
        float bias = l1b[c];
        for (int m = 0; m < 4; ++m)
            for (int r = 0; r < 4; ++r) {
                int row = m * 16 + lg * 4 + r;
                float v = acc[m][ot][r] + bias; v = v > 0.f ? v : 0.f;
                *(unsigned short*)(lds + row * 768 + ((c * 2) ^ ((row & 7) << 4))) = f2bf(v);
            }
    }
    __syncthreads();

    // lin2: wave w owns rows [16w, 16w+16), 48 padded cols
    f32x4 acc2[3];
    for (int ot = 0; ot < 3; ++ot) acc2[ot] = {0.f, 0.f, 0.f, 0.f};
    for (int ks = 0; ks < 12; ++ks) {
        int row = w * 16 + l15;
        bf16x8 A = *(const bf16x8*)(lds + row * 768 + ((ks * 64 + lg * 16) ^ ((row & 7) << 4)));
        for (int ot = 0; ot < 3; ++ot) {
            int c = ot * 16 + l15;
            bf16x8 B = *(const bf16x8*)(l2t + (size_t)c * 384 + ks * 32 + lg * 8);
            acc2[ot] = __builtin_amdgcn_mfma_f32_16x16x32_bf16(A, B, acc2[ot], 0, 0, 0);
        }
    }

    // bias + log_softmax over 40 classes (row spread over 16 lanes x 3 regs)
    int c0 = l15;
    for (int r = 0; r < 4; ++r) {
        float v0 = acc2[0][r] + l2b[c0];
        float v1 = acc2[1][r] + l2b[c0 + 16];
        float v2 = (c0 < 8) ? (acc2[2][r] + l2b[c0 + 32]) : -1e30f;
        float mx = fmaxf(fmaxf(v0, v1), v2);
        for (int msk = 1; msk < 16; msk <<= 1) mx = fmaxf(mx, __shfl_xor(mx, msk));
        float s = __expf(v0 - mx) + __expf(v1 - mx) + ((c0 < 8) ? __expf(v2 - mx) : 0.f);
        for (int msk = 1; msk < 16; msk <<= 1) s += __shfl_xor(s, msk);
        float lse = mx + __logf(s);
        int node = nbase + w * 16 + lg * 4 + r;
        if (node < N_NODES) {
            out[(size_t)node * 40 + c0] = v0 - lse;
            out[(size_t)node * 40 + c0 + 16] = v1 - lse;
            if (c0 < 8) out[(size_t)node * 40 + c0 + 32] = v2 - lse;
        }
    }
}

extern "C" void kernel_launch(void* const* d_in, const int* in_sizes, int n_in,
                              void* d_out, int out_size, void* d_ws, size_t ws_size,
                              hipStream_t stream) {
    const float* x  = (const float*)d_in[0];
    const int*   ei = (const int*)d_in[1];
    const float* gw1[3] = {(const float*)d_in[2],  (const float*)d_in[6],  (const float*)d_in[10]};
    const float* gb1[3] = {(const float*)d_in[3],  (const float*)d_in[7],  (const float*)d_in[11]};
    const float* gw2[3] = {(const float*)d_in[4],  (const float*)d_in[8],  (const float*)d_in[12]};
    const float* gb2[3] = {(const float*)d_in[5],  (const float*)d_in[9],  (const float*)d_in[13]};
    const float* l1w = (const float*)d_in[14];
    const float* l1b = (const float*)d_in[15];
    const float* l2w = (const float*)d_in[16];
    const float* l2b = (const float*)d_in[17];
    float* out = (float*)d_out;

    char* p = (char*)d_ws;
    auto alloc = [&](size_t bytes) { char* q = p; p += (bytes + 255) & ~(size_t)255; return q; };
    int* rp   = (int*)alloc(4 * (N_NODES + 1));
    int* cnt  = (int*)alloc(4 * N_NODES);
    int* bsum = (int*)alloc(4 * 256);
    int* colv = (int*)alloc(4 * (size_t)NEDGE);
    unsigned short* t  = (unsigned short*)alloc(2 * (size_t)N_NODES * 128);
    unsigned short* h1 = (unsigned short*)alloc(2 * (size_t)N_NODES * 128);
    unsigned short* h2 = (unsigned short*)alloc(2 * (size_t)N_NODES * 128);
    unsigned short* h3 = (unsigned short*)alloc(2 * (size_t)N_NODES * 128);
    unsigned short* wt[6];
    for (int i = 0; i < 6; ++i) wt[i] = (unsigned short*)alloc(2 * 128 * 128);
    unsigned short* l1t = (unsigned short*)alloc(2 * 384 * 384);
    unsigned short* l2t = (unsigned short*)alloc(2 * 48 * 384);

    const int nb = (N_NODES + 1023) / 1024;     // 98
    // CSR build
    k_zero<<<(N_NODES + 255) / 256, 256, 0, stream>>>(cnt, N_NODES);
    k_count<<<(NEDGE + 255) / 256, 256, 0, stream>>>(ei, cnt);
    k_scan1<<<nb, 256, 0, stream>>>(cnt, rp, bsum);
    k_scan2<<<1, 256, 0, stream>>>(bsum, nb);
    k_scan3<<<nb, 256, 0, stream>>>(rp, bsum);
    k_zero<<<(N_NODES + 255) / 256, 256, 0, stream>>>(cnt, N_NODES);
    k_fill<<<(NEDGE + 255) / 256, 256, 0, stream>>>(ei, rp, cnt, colv);

    // weight prep (transpose + bf16)
    for (int i = 0; i < 3; ++i) {
        k_wprep<<<(128 * 128 + 255) / 256, 256, 0, stream>>>(gw1[i], wt[2 * i], 128, 128, 128);
        k_wprep<<<(128 * 128 + 255) / 256, 256, 0, stream>>>(gw2[i], wt[2 * i + 1], 128, 128, 128);
    }
    k_wprep<<<(384 * 384 + 255) / 256, 256, 0, stream>>>(l1w, l1t, 384, 384, 384);
    k_wprep<<<(384 * 48 + 255) / 256, 256, 0, stream>>>(l2w, l2t, 384, 40, 48);

    const int gagg = (N_NODES + 3) / 4;
    const int gtile = (N_NODES + 63) / 64;
    // layer 1
    k_agg<1><<<gagg, 256, 0, stream>>>(x, t, rp, colv);
    k_mlp<<<gtile, 256, 0, stream>>>(t, wt[0], gb1[0], wt[1], gb2[0], h1);
    // layer 2
    k_agg<0><<<gagg, 256, 0, stream>>>(h1, t, rp, colv);
    k_mlp<<<gtile, 256, 0, stream>>>(t, wt[2], gb1[1], wt[3], gb2[1], h2);
    // layer 3
    k_agg<0><<<gagg, 256, 0, stream>>>(h2, t, rp, colv);
    k_mlp<<<gtile, 256, 0, stream>>>(t, wt[4], gb1[2], wt[5], gb2[2], h3);
    // head
    k_final<<<gtile, 256, 0, stream>>>(h1, h2, h3, l1t, l1b, l2t, l2b, out);
}